// Round 1
// baseline (894.678 us; speedup 1.0000x reference)
//
#include <hip/hip_runtime.h>

#define IMG_H 512
#define IMG_W 512
#define TX 64
#define TY 64
#define VCOLS 76      // TX + 12 halo
#define VSTR 80       // 80*4 = 320 B rows: 16B-aligned -> ds_read_b128 in phase 2

__global__ __launch_bounds__(256, 6) void boxblur_kernel(
    const float* __restrict__ in, const float* __restrict__ kern,
    float* __restrict__ out) {
    __shared__ __align__(16) float v_s[TY * VSTR];  // 64*80*4 = 20480 B

    const int tid = threadIdx.x;
    const int x0 = blockIdx.x * TX;
    const int y0 = blockIdx.y * TY;
    const size_t plane = (size_t)blockIdx.z * (size_t)(IMG_H * IMG_W);
    const float* __restrict__ inp = in + plane;

    // ---- phase 1: vertical 13-box sums, global -> v_s (coalesced loads) ----
    // tasks: 76 cols x 4 row-segments of 16 outputs = 304
    if (blockIdx.y != 0 && blockIdx.y != (IMG_H / TY) - 1) {
        // interior-y fast path: no gy reflect possible, 32-bit offsets
        for (int task = tid; task < VCOLS * 4; task += 256) {
            int c = task % VCOLS;      // consecutive lanes -> consecutive cols
            int s = task / VCOLS;
            int gx = x0 - 6 + c;
            gx = gx < 0 ? -gx : (gx > IMG_W - 1 ? 2 * (IMG_W - 1) - gx : gx);
            int yb = y0 + s * 16;      // first output row of this segment
            unsigned base = (unsigned)(yb - 6) * IMG_W + (unsigned)gx;
            float a[28];
            #pragma unroll
            for (int k = 0; k < 28; ++k)
                a[k] = inp[base + (unsigned)(k * IMG_W)];
            float sum = 0.f;
            #pragma unroll
            for (int k = 0; k < 13; ++k) sum += a[k];
            v_s[(s * 16) * VSTR + c] = sum;
            #pragma unroll
            for (int t = 1; t < 16; ++t) {
                sum += a[t + 12] - a[t - 1];
                v_s[(s * 16 + t) * VSTR + c] = sum;
            }
        }
    } else {
        // y-border path: reflect clamp on gy per load
        for (int task = tid; task < VCOLS * 4; task += 256) {
            int c = task % VCOLS;
            int s = task / VCOLS;
            int gx = x0 - 6 + c;
            gx = gx < 0 ? -gx : (gx > IMG_W - 1 ? 2 * (IMG_W - 1) - gx : gx);
            int yb = y0 + s * 16;
            float a[28];
            #pragma unroll
            for (int k = 0; k < 28; ++k) {
                int gy = yb - 6 + k;
                gy = gy < 0 ? -gy : (gy > IMG_H - 1 ? 2 * (IMG_H - 1) - gy : gy);
                a[k] = inp[(unsigned)gy * IMG_W + (unsigned)gx];
            }
            float sum = 0.f;
            #pragma unroll
            for (int k = 0; k < 13; ++k) sum += a[k];
            v_s[(s * 16) * VSTR + c] = sum;
            #pragma unroll
            for (int t = 1; t < 16; ++t) {
                sum += a[t + 12] - a[t - 1];
                v_s[(s * 16 + t) * VSTR + c] = sum;
            }
        }
    }
    __syncthreads();

    // ---- phase 2: horizontal 13-box over v_s, direct float4 stores ----
    // 1024 float4-outputs: 64 rows x 16 col-groups; 4 per thread.
    // Per 16-lane group: 4 consecutive float4 cols of one row -> 256 B
    // contiguous global store. LDS reads are 4x ds_read_b128, bank-uniform.
    {
        const float scale = kern[0];
        float* __restrict__ outp = out + plane;
        const int g = tid & 15;        // column group (4 cols)
        const int rb = tid >> 4;       // row base 0..15
        #pragma unroll
        for (int i = 0; i < 4; ++i) {
            const int r = i * 16 + rb;
            const float* vrow = &v_s[r * VSTR + 4 * g];  // covers out cols 4g..4g+3
            float4 v0 = *(const float4*)(vrow);
            float4 v1 = *(const float4*)(vrow + 4);
            float4 v2 = *(const float4*)(vrow + 8);
            float4 v3 = *(const float4*)(vrow + 12);
            // s0 = sum of v[0..12]
            float s0 = (((v0.x + v0.y) + (v0.z + v0.w))
                      + ((v1.x + v1.y) + (v1.z + v1.w)))
                      + (((v2.x + v2.y) + (v2.z + v2.w)) + v3.x);
            float s1 = s0 + v3.y - v0.x;
            float s2 = s1 + v3.z - v0.y;
            float s3 = s2 + v3.w - v0.z;
            float4 o;
            o.x = s0 * scale; o.y = s1 * scale; o.z = s2 * scale; o.w = s3 * scale;
            *(float4*)(outp + (size_t)(y0 + r) * IMG_W + x0 + 4 * g) = o;
        }
    }
}

extern "C" void kernel_launch(void* const* d_in, const int* in_sizes, int n_in,
                              void* d_out, int out_size, void* d_ws, size_t ws_size,
                              hipStream_t stream) {
    const float* x = (const float*)d_in[0];
    const float* k = (const float*)d_in[1];
    float* out = (float*)d_out;
    dim3 grid(IMG_W / TX, IMG_H / TY, 8 * 64);  // x-tiles, y-tiles, B*C planes
    dim3 block(256);
    boxblur_kernel<<<grid, block, 0, stream>>>(x, k, out);
}

// Round 4
// 891.840 us; speedup vs baseline: 1.0032x; 1.0032x over previous
//
#include <hip/hip_runtime.h>

#define IMG_H 512
#define IMG_W 512
#define TX 64
#define TY 64
#define VCOLS 76      // TX + 12 halo
#define VSTR 80       // 80*4 = 320 B rows: 16B-aligned -> ds_read_b128 in phase 2
#define NTILES_X (IMG_W / TX)          // 8
#define NTILES_Y (IMG_H / TY)          // 8
#define NPLANES (8 * 64)               // 512
#define NWG (NTILES_X * NTILES_Y * NPLANES)  // 32768
#define NXCD 8
#define CHUNK (NWG / NXCD)             // 4096

__global__ __launch_bounds__(256) void boxblur_kernel(
    const float* __restrict__ in, const float* __restrict__ kern,
    float* __restrict__ out) {
    __shared__ __align__(16) float v_s[TY * VSTR];  // 64*80*4 = 20480 B

    const int tid = threadIdx.x;

    // XCD-chunked swizzle: round-robin dispatch (wg%8 -> XCD) becomes
    // "XCD k owns contiguous chunk k*4096..k*4096+4095" = 64 whole planes.
    // All 64 tiles of a plane then share one XCD's L2 -> halo re-reads hit L2.
    const int wg = (int)blockIdx.x;
    const int swz = (wg & (NXCD - 1)) * CHUNK + (wg >> 3);
    const int bx = swz & (NTILES_X - 1);
    const int by = (swz >> 3) & (NTILES_Y - 1);
    const int bz = swz >> 6;

    const int x0 = bx * TX;
    const int y0 = by * TY;
    const size_t plane = (size_t)bz * (size_t)(IMG_H * IMG_W);
    const float* __restrict__ inp = in + plane;

    // ---- phase 1: vertical 13-box sums, global -> v_s (coalesced loads) ----
    // tasks: 76 cols x 4 row-segments of 16 outputs = 304
    if (by != 0 && by != NTILES_Y - 1) {
        // interior-y fast path: no gy reflect possible, 32-bit offsets
        for (int task = tid; task < VCOLS * 4; task += 256) {
            int c = task % VCOLS;      // consecutive lanes -> consecutive cols
            int s = task / VCOLS;
            int gx = x0 - 6 + c;
            gx = gx < 0 ? -gx : (gx > IMG_W - 1 ? 2 * (IMG_W - 1) - gx : gx);
            int yb = y0 + s * 16;      // first output row of this segment
            unsigned base = (unsigned)(yb - 6) * IMG_W + (unsigned)gx;
            float a[28];
            #pragma unroll
            for (int k = 0; k < 28; ++k)
                a[k] = inp[base + (unsigned)(k * IMG_W)];
            float sum = 0.f;
            #pragma unroll
            for (int k = 0; k < 13; ++k) sum += a[k];
            v_s[(s * 16) * VSTR + c] = sum;
            #pragma unroll
            for (int t = 1; t < 16; ++t) {
                sum += a[t + 12] - a[t - 1];
                v_s[(s * 16 + t) * VSTR + c] = sum;
            }
        }
    } else {
        // y-border path: reflect clamp on gy per load
        for (int task = tid; task < VCOLS * 4; task += 256) {
            int c = task % VCOLS;
            int s = task / VCOLS;
            int gx = x0 - 6 + c;
            gx = gx < 0 ? -gx : (gx > IMG_W - 1 ? 2 * (IMG_W - 1) - gx : gx);
            int yb = y0 + s * 16;
            float a[28];
            #pragma unroll
            for (int k = 0; k < 28; ++k) {
                int gy = yb - 6 + k;
                gy = gy < 0 ? -gy : (gy > IMG_H - 1 ? 2 * (IMG_H - 1) - gy : gy);
                a[k] = inp[(unsigned)gy * IMG_W + (unsigned)gx];
            }
            float sum = 0.f;
            #pragma unroll
            for (int k = 0; k < 13; ++k) sum += a[k];
            v_s[(s * 16) * VSTR + c] = sum;
            #pragma unroll
            for (int t = 1; t < 16; ++t) {
                sum += a[t + 12] - a[t - 1];
                v_s[(s * 16 + t) * VSTR + c] = sum;
            }
        }
    }
    __syncthreads();

    // ---- phase 2: horizontal 13-box over v_s, direct float4 stores ----
    // 1024 float4-outputs: 64 rows x 16 col-groups; 4 per thread.
    // Per 16-lane group: 4 consecutive float4 cols of one row -> 256 B
    // contiguous global store. LDS reads are 4x ds_read_b128.
    {
        const float scale = kern[0];
        float* __restrict__ outp = out + plane;
        const int g = tid & 15;        // column group (4 cols)
        const int rb = tid >> 4;       // row base 0..15
        #pragma unroll
        for (int i = 0; i < 4; ++i) {
            const int r = i * 16 + rb;
            const float* vrow = &v_s[r * VSTR + 4 * g];  // out cols 4g..4g+3
            float4 v0 = *(const float4*)(vrow);
            float4 v1 = *(const float4*)(vrow + 4);
            float4 v2 = *(const float4*)(vrow + 8);
            float4 v3 = *(const float4*)(vrow + 12);
            // s0 = sum of v[0..12]
            float s0 = (((v0.x + v0.y) + (v0.z + v0.w))
                      + ((v1.x + v1.y) + (v1.z + v1.w)))
                      + (((v2.x + v2.y) + (v2.z + v2.w)) + v3.x);
            float s1 = s0 + v3.y - v0.x;
            float s2 = s1 + v3.z - v0.y;
            float s3 = s2 + v3.w - v0.z;
            float4 o;
            o.x = s0 * scale; o.y = s1 * scale; o.z = s2 * scale; o.w = s3 * scale;
            *(float4*)(outp + (size_t)(y0 + r) * IMG_W + x0 + 4 * g) = o;
        }
    }
}

extern "C" void kernel_launch(void* const* d_in, const int* in_sizes, int n_in,
                              void* d_out, int out_size, void* d_ws, size_t ws_size,
                              hipStream_t stream) {
    const float* x = (const float*)d_in[0];
    const float* k = (const float*)d_in[1];
    float* out = (float*)d_out;
    dim3 grid(NWG, 1, 1);   // 1D grid, XCD-chunked swizzle inside kernel
    dim3 block(256);
    boxblur_kernel<<<grid, block, 0, stream>>>(x, k, out);
}